// Round 11
// baseline (156.859 us; speedup 1.0000x reference)
//
#include <hip/hip_runtime.h>
#include <math.h>
#include <stdint.h>

// SpikingSelfAttention on MI355X — event-driven (spike-sparsity-aware).
// [pool8+transpose | wconv] -> QKV MFMA-GEMM (T2 XOR-swizzled LDS, T4
// counted-vmcnt double-buffer, spike -> 3MB bitmask + per-batch flags) ->
// attn (skipped for spike-free batches; expands bitmask) -> out GEMM (bias
// fast path, nontemporal stores) + BN + spike + repeat8.
// Correct for arbitrary inputs.

#define THRESH 2.0f
#define BN_EPS 1e-5f

typedef __attribute__((ext_vector_type(4))) float f32x4;
typedef __attribute__((ext_vector_type(8))) short bfrag;   // 8 bf16
typedef __attribute__((ext_vector_type(4))) short s16x4;   // 4 bf16

__device__ __forceinline__ short f2bf(float f) {  // RNE f32->bf16
  union { float f; unsigned u; } v; v.f = f;
  unsigned r = (v.u + 0x7FFFu + ((v.u >> 16) & 1u)) >> 16;
  return (short)r;
}
__device__ __forceinline__ void gload16(const void* g, void* l) {
  __builtin_amdgcn_global_load_lds(
      (const __attribute__((address_space(1))) void*)g,
      (__attribute__((address_space(3))) void*)l, 16, 0, 0);
}
__device__ __forceinline__ void nt_store4(float* p, float s) {
  f32x4 v = {s, s, s, s};
  __builtin_nontemporal_store(v, (f32x4*)p);
}

// ---- pool8 + transpose (z<32): x(32,512,4096)f32 -> xpT(32,512t,512c)bf16
// ---- wconv slice (z==32): W_qkv,W_out f32 -> bf16; zero flags
__global__ __launch_bounds__(256) void pool_wconv_kernel(
    const float* __restrict__ x, short* __restrict__ xpT,
    const float* __restrict__ wq, const float* __restrict__ wo,
    short* __restrict__ wqb, short* __restrict__ wob, int* __restrict__ flags) {
  if (blockIdx.z == 32) {
    const int gb = blockIdx.y * 8 + blockIdx.x;       // 0..63
    const int base = gb * 256 + threadIdx.x;          // 0..16383
    if (base < 32) flags[base] = 0;
    const int n1 = 1536 * 512 / 4, ntot = n1 + 512 * 512 / 4;
    for (int i = base; i < ntot; i += 16384) {
      f32x4 v; s16x4 h;
      if (i < n1) {
        v = ((const f32x4*)wq)[i];
        h.x = f2bf(v.x); h.y = f2bf(v.y); h.z = f2bf(v.z); h.w = f2bf(v.w);
        ((s16x4*)wqb)[i] = h;
      } else {
        int j = i - n1;
        v = ((const f32x4*)wo)[j];
        h.x = f2bf(v.x); h.y = f2bf(v.y); h.z = f2bf(v.z); h.w = f2bf(v.w);
        ((s16x4*)wob)[j] = h;
      }
    }
    return;
  }
  const int b = blockIdx.z, c0 = blockIdx.y * 64, t0 = blockIdx.x * 64;
  __shared__ float Ts[64][65];
  const int tid = threadIdx.x;
  const int tl = tid & 63, cb = tid >> 6;
  const float* xb = x + (size_t)b * 512 * 4096;
#pragma unroll
  for (int i = 0; i < 16; ++i) {
    int cl = cb * 16 + i;
    const float* p = xb + (size_t)(c0 + cl) * 4096 + (size_t)(t0 + tl) * 8;
    float4 a = *(const float4*)p, d = *(const float4*)(p + 4);
    Ts[tl][cl] = (((a.x + a.y) + (a.z + a.w)) + ((d.x + d.y) + (d.z + d.w))) * 0.125f;
  }
  __syncthreads();
  const int row = tid >> 2, cs = (tid & 3) * 16;
  short* dst = xpT + ((size_t)b * 512 + t0 + row) * 512 + c0 + cs;
#pragma unroll
  for (int k = 0; k < 4; ++k) {
    s16x4 h;
    h.x = f2bf(Ts[row][cs + 4 * k + 0]);
    h.y = f2bf(Ts[row][cs + 4 * k + 1]);
    h.z = f2bf(Ts[row][cs + 4 * k + 2]);
    h.w = f2bf(Ts[row][cs + 4 * k + 3]);
    ((s16x4*)dst)[k] = h;
  }
}

// ------- QKV GEMM (bf16 MFMA, T2 swizzle + T4 dbuf/counted-vmcnt) -----------
// C[o,t] = sum_c W[o,c]*xpT[t,c]; 128x128 tile, BK=64, 4 waves, 2 LDS bufs.
// Stage src seg^(row&7) -> linear LDS; read col^((row&7)<<3).
__global__ __launch_bounds__(256, 2) void qkv_gemm_mfma(
    const short* __restrict__ Wb, const short* __restrict__ XTb,
    const float* __restrict__ Wf, const float* __restrict__ x,
    uint8_t* __restrict__ mask, int* __restrict__ flags) {
  const int b = blockIdx.z, o0 = blockIdx.y * 128, t0 = blockIdx.x * 128;
  __shared__ __align__(16) short S[4][128 * 64];  // A0,B0,A1,B1 (64 KiB)
  const int tid = threadIdx.x, lane = tid & 63, wave = tid >> 6;
  const int wr = (wave >> 1) * 64, wc = (wave & 1) * 64;
  const int lrow = lane & 15, lk = (lane >> 4) * 8;
  f32x4 acc[4][4] = {};
  const short* Ag = Wb + (size_t)o0 * 512;
  const short* Bg = XTb + ((size_t)b * 512 + (size_t)t0) * 512;

#define STAGE(bufA, k0)                                                        \
  _Pragma("unroll") for (int i_ = 0; i_ < 4; ++i_) {                           \
    int idx_ = tid + 256 * i_, row_ = idx_ >> 3, seg_ = idx_ & 7;              \
    int ss_ = seg_ ^ (row_ & 7);                                               \
    gload16(Ag + (size_t)row_ * 512 + (k0) + ss_ * 8, S[bufA] + idx_ * 8);     \
    gload16(Bg + (size_t)row_ * 512 + (k0) + ss_ * 8, S[(bufA) + 1] + idx_ * 8); \
  }

  STAGE(0, 0);  // prologue: buf0 <- K-tile 0 (8 loads in flight/thread)
#pragma unroll
  for (int it = 0; it < 8; ++it) {
    const int cur = (it & 1) * 2;
    if (it < 7) {
      STAGE(2 - cur, (it + 1) * 64);  // next tile: 8 more loads in flight
      asm volatile("s_waitcnt vmcnt(8)" ::: "memory");  // current tile landed
    } else {
      asm volatile("s_waitcnt vmcnt(0)" ::: "memory");
    }
    __builtin_amdgcn_s_barrier();
    const short* Ac = S[cur];
    const short* Bc = S[cur + 1];
#pragma unroll
    for (int kk = 0; kk < 64; kk += 32) {
      bfrag af[4], bfr[4];
#pragma unroll
      for (int mi = 0; mi < 4; ++mi) {
        int row = wr + mi * 16 + lrow;
        af[mi] = *(const bfrag*)(Ac + row * 64 + ((kk + lk) ^ ((row & 7) << 3)));
      }
#pragma unroll
      for (int ni = 0; ni < 4; ++ni) {
        int row = wc + ni * 16 + lrow;
        bfr[ni] = *(const bfrag*)(Bc + row * 64 + ((kk + lk) ^ ((row & 7) << 3)));
      }
#pragma unroll
      for (int mi = 0; mi < 4; ++mi)
#pragma unroll
        for (int ni = 0; ni < 4; ++ni)
          acc[mi][ni] = __builtin_amdgcn_mfma_f32_16x16x32_bf16(
              af[mi], bfr[ni], acc[mi][ni], 0, 0, 0);
    }
    __builtin_amdgcn_s_barrier();  // all reads done; buffer may be restaged
  }
#undef STAGE

  // Epilogue: spikes into LDS bounce, exact fallback, then 3MB bitmask.
  __syncthreads();
  short* Cs = S[0];  // reuse: C[128 o][128 t] bf16 spike values
  const int lrg = (lane >> 4) * 4;
  unsigned long long fb = 0;
  bool anyspike = false;
#pragma unroll
  for (int mi = 0; mi < 4; ++mi)
#pragma unroll
    for (int ni = 0; ni < 4; ++ni)
#pragma unroll
      for (int r = 0; r < 4; ++r) {
        int rowl = wr + mi * 16 + lrg + r;
        int coll = wc + ni * 16 + lrow;
        float v = acc[mi][ni][r];
        if (fabsf(v - THRESH) < 0.05f) fb |= 1ull << (mi * 16 + ni * 4 + r);
        else anyspike |= (v >= THRESH);
        Cs[rowl * 128 + coll] = (v >= THRESH) ? (short)0x3F80 : (short)0;
      }
  if (__builtin_expect(fb != 0, 0)) {  // exact fp32 recompute, ~never taken
    for (int bit = 0; bit < 64; ++bit) {
      if (!((fb >> bit) & 1)) continue;
      int mi = bit >> 4, ni = (bit >> 2) & 3, r = bit & 3;
      int rowl = wr + mi * 16 + lrg + r;
      int coll = wc + ni * 16 + lrow;
      const float* wrow = Wf + (size_t)(o0 + rowl) * 512;
      const float* xcol = x + (size_t)b * 512 * 4096 + (size_t)(t0 + coll) * 8;
      float s = 0.f;
      for (int c = 0; c < 512; ++c) {
        const float* xc = xcol + (size_t)c * 4096;
        float p = ((xc[0] + xc[1]) + (xc[2] + xc[3])) +
                  ((xc[4] + xc[5]) + (xc[6] + xc[7]));
        s += wrow[c] * (p * 0.125f);
      }
      bool sp = (s >= THRESH);
      anyspike |= sp;
      Cs[rowl * 128 + coll] = sp ? (short)0x3F80 : (short)0;
    }
  }
  __syncthreads();
  {
    // compress: row = tid>>1 (128 o-rows), half = tid&1 (64 t each)
    const int row = tid >> 1, half = tid & 1;
    unsigned long long bits = 0;
#pragma unroll
    for (int j = 0; j < 8; ++j) {
      bfrag v = *(const bfrag*)(Cs + row * 128 + half * 64 + j * 8);
#pragma unroll
      for (int k = 0; k < 8; ++k)
        bits |= (unsigned long long)(v[k] != 0) << (j * 8 + k);
    }
    *(unsigned long long*)(mask + ((size_t)b * 1536 + o0 + row) * 64 +
                           (t0 >> 3) + half * 8) = bits;
  }
  unsigned long long bal = __ballot(anyspike);
  if (lane == 0 && bal != 0ull) atomicOr(&flags[b], 1);
}

// ------- attention (cold: only for batches with spikes). Expands the spike
// bitmask to bf16/f32; M = V K^T (bf16 MFMA, exact on binary spikes),
// O = scale * M Q (fp32); emits attT f32 + attTb bf16.
__global__ __launch_bounds__(256) void attn_kernel(const uint8_t* __restrict__ mask,
                                                   float* __restrict__ attT,
                                                   short* __restrict__ attTb,
                                                   const int* __restrict__ flags) {
  const int b = blockIdx.z, h = blockIdx.y, th = blockIdx.x;  // th: t-half
  if (flags[b] == 0) return;  // no spikes in this batch -> attn output is 0
  const uint8_t* Qm = mask + ((size_t)b * 1536 + h * 64) * 64;
  const uint8_t* Km = mask + ((size_t)b * 1536 + 512 + h * 64) * 64;
  const uint8_t* Vm = mask + ((size_t)b * 1536 + 1024 + h * 64) * 64;

  __shared__ float Ms[64][65];  // Ms[e][d]
  __shared__ float Qs[64][65];  // Qs[e][tloc]
  __shared__ float Ts[64][65];  // Ts[tloc][d]

  const int tid = threadIdx.x, lane = tid & 63, wave = tid >> 6;
  const int lrow = lane & 15, lk = (lane >> 4) * 8, lrg = (lane >> 4) * 4;

  f32x4 mAcc[4] = {};
  for (int kk = 0; kk < 512; kk += 32) {
    uint8_t mv = Vm[(wave * 16 + lrow) * 64 + ((kk + lk) >> 3)];
    bfrag a;
#pragma unroll
    for (int j = 0; j < 8; ++j) a[j] = ((mv >> j) & 1) ? (short)0x3F80 : (short)0;
#pragma unroll
    for (int ni = 0; ni < 4; ++ni) {
      uint8_t mk = Km[(ni * 16 + lrow) * 64 + ((kk + lk) >> 3)];
      bfrag bb;
#pragma unroll
      for (int j = 0; j < 8; ++j) bb[j] = ((mk >> j) & 1) ? (short)0x3F80 : (short)0;
      mAcc[ni] = __builtin_amdgcn_mfma_f32_16x16x32_bf16(a, bb, mAcc[ni], 0, 0, 0);
    }
  }
#pragma unroll
  for (int ni = 0; ni < 4; ++ni)
#pragma unroll
    for (int r = 0; r < 4; ++r)
      Ms[ni * 16 + lrow][wave * 16 + lrg + r] = mAcc[ni][r];
  __syncthreads();

  const int tx = tid & 15, ty = tid >> 4;
  const int srow = tid >> 2, scseg = (tid & 3) * 16;
  for (int tt = th * 256; tt < th * 256 + 256; tt += 64) {
    {
      uint8_t b0 = Qm[srow * 64 + ((tt + scseg) >> 3)];
      uint8_t b1 = Qm[srow * 64 + ((tt + scseg) >> 3) + 1];
#pragma unroll
      for (int j = 0; j < 8; ++j) {
        Qs[srow][scseg + j] = (float)((b0 >> j) & 1);
        Qs[srow][scseg + 8 + j] = (float)((b1 >> j) & 1);
      }
    }
    __syncthreads();
    float acc[4][4] = {};
#pragma unroll
    for (int e = 0; e < 64; ++e) {
      float4 md = *reinterpret_cast<const float4*>(&Ms[e][ty << 2]);
      float4 qt = *reinterpret_cast<const float4*>(&Qs[e][tx << 2]);
      float mr[4] = {md.x, md.y, md.z, md.w};
      float qr[4] = {qt.x, qt.y, qt.z, qt.w};
#pragma unroll
      for (int i = 0; i < 4; ++i)
#pragma unroll
        for (int j = 0; j < 4; ++j) acc[i][j] += mr[i] * qr[j];
    }
#pragma unroll
    for (int i = 0; i < 4; ++i)
#pragma unroll
      for (int j = 0; j < 4; ++j)
        Ts[(tx << 2) + j][(ty << 2) + i] = acc[i][j] * 0.125f;
    __syncthreads();
    {
      float* dst = attT + ((size_t)b * 512 + tt + srow) * 512 + h * 64 + scseg;
      short* dstb = attTb + ((size_t)b * 512 + tt + srow) * 512 + h * 64 + scseg;
#pragma unroll
      for (int k = 0; k < 4; ++k) {
        float4 v = *reinterpret_cast<const float4*>(&Ts[srow][scseg + 4 * k]);
        *reinterpret_cast<float4*>(dst + 4 * k) = v;
        s16x4 hh;
        hh.x = f2bf(v.x); hh.y = f2bf(v.y); hh.z = f2bf(v.z); hh.w = f2bf(v.w);
        ((s16x4*)dstb)[k] = hh;
      }
    }
    __syncthreads();
  }
}

// ------- out GEMM + BN + spike + repeat8; bias fast path (nontemporal) ------
__global__ __launch_bounds__(256) void out_gemm_mfma(
    const short* __restrict__ Wob, const short* __restrict__ attTb,
    const float* __restrict__ Wf, const float* __restrict__ attT,
    const float* __restrict__ gamma, const float* __restrict__ beta,
    const float* __restrict__ mean, const float* __restrict__ var,
    float* __restrict__ out, const int* __restrict__ flags) {
  const int b = blockIdx.z, o0 = blockIdx.y * 128, t0 = blockIdx.x * 128;
  const int tid = threadIdx.x;

  if (flags[b] == 0) {
    // attn output is exactly 0 -> y = beta - mean*inv, uniform over t (and b).
    __shared__ float sRow[128];
    if (tid < 128) {
      int o = o0 + tid;
      float inv = gamma[o] / sqrtf(var[o] + BN_EPS);
      float y = beta[o] - mean[o] * inv;
      sRow[tid] = (y >= THRESH) ? 1.0f : 0.0f;
    }
    __syncthreads();
    float* base = out + ((size_t)b * 512 + o0) * 4096 + (size_t)t0 * 8;
    for (int r = 0; r < 128; ++r) {
      float s = sRow[r];
      nt_store4(base + (size_t)r * 4096 + tid * 4, s);
    }
    return;
  }

  __shared__ __align__(16) short Asm[128 * 64];
  __shared__ __align__(16) short Bsm[128 * 64];
  const int lane = tid & 63, wave = tid >> 6;
  const int wr = (wave >> 1) * 64, wc = (wave & 1) * 64;
  const int lrow = lane & 15, lk = (lane >> 4) * 8;
  f32x4 acc[4][4] = {};
  const short* Ag = Wob + (size_t)o0 * 512;
  const short* Bg = attTb + ((size_t)b * 512 + t0) * 512;

  for (int k0 = 0; k0 < 512; k0 += 64) {
    __syncthreads();
#pragma unroll
    for (int i = 0; i < 4; ++i) {
      int idx = tid + 256 * i, row = idx >> 3, seg = idx & 7;
      int sseg = seg ^ (row & 7);
      gload16(Ag + (size_t)row * 512 + k0 + sseg * 8, Asm + idx * 8);
    }
#pragma unroll
    for (int i = 0; i < 4; ++i) {
      int idx = tid + 256 * i, row = idx >> 3, seg = idx & 7;
      int sseg = seg ^ (row & 7);
      gload16(Bg + (size_t)row * 512 + k0 + sseg * 8, Bsm + idx * 8);
    }
    __syncthreads();
#pragma unroll
    for (int kk = 0; kk < 64; kk += 32) {
      bfrag af[4], bfr[4];
#pragma unroll
      for (int mi = 0; mi < 4; ++mi) {
        int row = wr + mi * 16 + lrow;
        af[mi] = *(const bfrag*)(Asm + row * 64 + ((kk + lk) ^ ((row & 7) << 3)));
      }
#pragma unroll
      for (int ni = 0; ni < 4; ++ni) {
        int row = wc + ni * 16 + lrow;
        bfr[ni] = *(const bfrag*)(Bsm + row * 64 + ((kk + lk) ^ ((row & 7) << 3)));
      }
#pragma unroll
      for (int mi = 0; mi < 4; ++mi)
#pragma unroll
        for (int ni = 0; ni < 4; ++ni)
          acc[mi][ni] = __builtin_amdgcn_mfma_f32_16x16x32_bf16(
              af[mi], bfr[ni], acc[mi][ni], 0, 0, 0);
    }
  }

  const int lrg = (lane >> 4) * 4;
  unsigned long long fbm = 0;
#pragma unroll
  for (int mi = 0; mi < 4; ++mi)
#pragma unroll
    for (int r = 0; r < 4; ++r) {
      const int o = o0 + wr + mi * 16 + lrg + r;
      const float inv = gamma[o] / sqrtf(var[o] + BN_EPS);
      const float bias = beta[o] - mean[o] * inv;
#pragma unroll
      for (int ni = 0; ni < 4; ++ni) {
        int tt = t0 + wc + ni * 16 + lrow;
        float y = acc[mi][ni][r] * inv + bias;
        if (fabsf(y - THRESH) < 0.02f) fbm |= 1ull << (mi * 16 + ni * 4 + r);
        float s = (y >= THRESH) ? 1.0f : 0.0f;
        float* dp = out + ((size_t)b * 512 + o) * 4096 + (size_t)tt * 8;
        nt_store4(dp, s);
        nt_store4(dp + 4, s);
      }
    }
  if (__builtin_expect(fbm != 0, 0)) {  // exact fp32 recompute, ~never taken
    for (int bit = 0; bit < 64; ++bit) {
      if (!((fbm >> bit) & 1)) continue;
      int mi = bit >> 4, ni = (bit >> 2) & 3, r = bit & 3;
      int o = o0 + wr + mi * 16 + lrg + r;
      int tt = t0 + wc + ni * 16 + lrow;
      const float* wrow = Wf + (size_t)o * 512;
      const float* arow = attT + ((size_t)b * 512 + tt) * 512;
      float s = 0.f;
      for (int c = 0; c < 512; ++c) s += wrow[c] * arow[c];
      float inv = gamma[o] / sqrtf(var[o] + BN_EPS);
      float y = s * inv + (beta[o] - mean[o] * inv);
      float sp = (y >= THRESH) ? 1.0f : 0.0f;
      float* dp = out + ((size_t)b * 512 + o) * 4096 + (size_t)tt * 8;
      nt_store4(dp, sp);
      nt_store4(dp + 4, sp);
    }
  }
}

extern "C" void kernel_launch(void* const* d_in, const int* in_sizes, int n_in,
                              void* d_out, int out_size, void* d_ws, size_t ws_size,
                              hipStream_t stream) {
  (void)in_sizes; (void)n_in; (void)out_size; (void)ws_size;
  const float* x     = (const float*)d_in[0];
  const float* w_qkv = (const float*)d_in[1];
  const float* w_out = (const float*)d_in[2];
  const float* gamma = (const float*)d_in[3];
  const float* beta  = (const float*)d_in[4];
  const float* mean  = (const float*)d_in[5];
  const float* var   = (const float*)d_in[6];
  float* outp = (float*)d_out;

  // d_out-front scratch: xpT bf16 (32,512t,512c) in [0,16MB) — consumed by
  // qkv BEFORE out_gemm writes d_out.
  // d_ws scratch (out_gemm inputs must NOT alias d_out):
  //   [0,32MB)   attT  f32  (32,512t,512c)
  //   [32,48MB)  attTb bf16 (32,512t,512c)
  //   [48MB)     Wqb bf16 (1536,512), [50MB) Wob bf16 (512,512),
  //   [51MB)     flags int[32], [52MB,+3MB) spike bitmask (32,1536,64B)
  char* ob = (char*)d_out;
  char* wb = (char*)d_ws;
  short* xpT  = (short*)(ob);
  float* attT  = (float*)(wb);
  short* attTb = (short*)(wb + ((size_t)32 << 20));
  short* Wqb   = (short*)(wb + ((size_t)48 << 20));
  short* Wob   = (short*)(wb + ((size_t)50 << 20));
  int*   flags = (int*)(wb + ((size_t)51 << 20));
  uint8_t* mask = (uint8_t*)(wb + ((size_t)52 << 20));

  pool_wconv_kernel<<<dim3(8, 8, 33), 256, 0, stream>>>(x, xpT, w_qkv, w_out,
                                                        Wqb, Wob, flags);
  qkv_gemm_mfma<<<dim3(4, 12, 32), 256, 0, stream>>>(Wqb, xpT, w_qkv, x, mask,
                                                     flags);
  attn_kernel<<<dim3(2, 8, 32), 256, 0, stream>>>(mask, attT, attTb, flags);
  out_gemm_mfma<<<dim3(4, 4, 32), 256, 0, stream>>>(Wob, attTb, w_out, attT,
                                                    gamma, beta, mean, var,
                                                    outp, flags);
}

// Round 12
// 148.551 us; speedup vs baseline: 1.0559x; 1.0559x over previous
//
#include <hip/hip_runtime.h>
#include <math.h>
#include <stdint.h>

// SpikingSelfAttention on MI355X — event-driven (spike-sparsity-aware).
// [pool8+transpose | wconv] -> QKV MFMA-GEMM (T2 XOR-swizzled LDS, single-
// buffered, spike -> 3MB bitmask + per-batch flags) -> attn (skipped for
// spike-free batches; expands bitmask) -> out GEMM (bias fast path,
// nontemporal stores) + BN + spike + repeat8. Correct for arbitrary inputs.

#define THRESH 2.0f
#define BN_EPS 1e-5f

typedef __attribute__((ext_vector_type(4))) float f32x4;
typedef __attribute__((ext_vector_type(8))) short bfrag;   // 8 bf16
typedef __attribute__((ext_vector_type(4))) short s16x4;   // 4 bf16

__device__ __forceinline__ short f2bf(float f) {  // RNE f32->bf16
  union { float f; unsigned u; } v; v.f = f;
  unsigned r = (v.u + 0x7FFFu + ((v.u >> 16) & 1u)) >> 16;
  return (short)r;
}
__device__ __forceinline__ void gload16(const void* g, void* l) {
  __builtin_amdgcn_global_load_lds(
      (const __attribute__((address_space(1))) void*)g,
      (__attribute__((address_space(3))) void*)l, 16, 0, 0);
}
__device__ __forceinline__ void nt_store4(float* p, float s) {
  f32x4 v = {s, s, s, s};
  __builtin_nontemporal_store(v, (f32x4*)p);
}

// ---- pool8 + transpose (z<32): x(32,512,4096)f32 -> xpT(32,512t,512c)bf16
// ---- wconv slice (z==32): W_qkv,W_out f32 -> bf16; zero flags
__global__ __launch_bounds__(256) void pool_wconv_kernel(
    const float* __restrict__ x, short* __restrict__ xpT,
    const float* __restrict__ wq, const float* __restrict__ wo,
    short* __restrict__ wqb, short* __restrict__ wob, int* __restrict__ flags) {
  if (blockIdx.z == 32) {
    const int gb = blockIdx.y * 8 + blockIdx.x;       // 0..63
    const int base = gb * 256 + threadIdx.x;          // 0..16383
    if (base < 32) flags[base] = 0;
    const int n1 = 1536 * 512 / 4, ntot = n1 + 512 * 512 / 4;
    for (int i = base; i < ntot; i += 16384) {
      f32x4 v; s16x4 h;
      if (i < n1) {
        v = ((const f32x4*)wq)[i];
        h.x = f2bf(v.x); h.y = f2bf(v.y); h.z = f2bf(v.z); h.w = f2bf(v.w);
        ((s16x4*)wqb)[i] = h;
      } else {
        int j = i - n1;
        v = ((const f32x4*)wo)[j];
        h.x = f2bf(v.x); h.y = f2bf(v.y); h.z = f2bf(v.z); h.w = f2bf(v.w);
        ((s16x4*)wob)[j] = h;
      }
    }
    return;
  }
  const int b = blockIdx.z, c0 = blockIdx.y * 64, t0 = blockIdx.x * 64;
  __shared__ float Ts[64][65];
  const int tid = threadIdx.x;
  const int tl = tid & 63, cb = tid >> 6;
  const float* xb = x + (size_t)b * 512 * 4096;
#pragma unroll
  for (int i = 0; i < 16; ++i) {
    int cl = cb * 16 + i;
    const float* p = xb + (size_t)(c0 + cl) * 4096 + (size_t)(t0 + tl) * 8;
    float4 a = *(const float4*)p, d = *(const float4*)(p + 4);
    Ts[tl][cl] = (((a.x + a.y) + (a.z + a.w)) + ((d.x + d.y) + (d.z + d.w))) * 0.125f;
  }
  __syncthreads();
  const int row = tid >> 2, cs = (tid & 3) * 16;
  short* dst = xpT + ((size_t)b * 512 + t0 + row) * 512 + c0 + cs;
#pragma unroll
  for (int k = 0; k < 4; ++k) {
    s16x4 h;
    h.x = f2bf(Ts[row][cs + 4 * k + 0]);
    h.y = f2bf(Ts[row][cs + 4 * k + 1]);
    h.z = f2bf(Ts[row][cs + 4 * k + 2]);
    h.w = f2bf(Ts[row][cs + 4 * k + 3]);
    ((s16x4*)dst)[k] = h;
  }
}

// ------- QKV GEMM (bf16 MFMA, T2-swizzled LDS) -> spike bitmask + flags -----
// C[o,t] = sum_c W[o,c]*xpT[t,c]; 128x128 tile, BK=64, 4 waves, 32KB LDS.
// Stage src seg^(row&7) -> linear LDS; read col^((row&7)<<3). (rule #21)
__global__ __launch_bounds__(256, 3) void qkv_gemm_mfma(
    const short* __restrict__ Wb, const short* __restrict__ XTb,
    const float* __restrict__ Wf, const float* __restrict__ x,
    uint8_t* __restrict__ mask, int* __restrict__ flags) {
  const int b = blockIdx.z, o0 = blockIdx.y * 128, t0 = blockIdx.x * 128;
  __shared__ __align__(16) short Asm[128 * 64];
  __shared__ __align__(16) short Bsm[128 * 64];
  const int tid = threadIdx.x, lane = tid & 63, wave = tid >> 6;
  const int wr = (wave >> 1) * 64, wc = (wave & 1) * 64;
  const int lrow = lane & 15, lk = (lane >> 4) * 8;
  f32x4 acc[4][4] = {};
  const short* Ag = Wb + (size_t)o0 * 512;
  const short* Bg = XTb + ((size_t)b * 512 + (size_t)t0) * 512;

  for (int k0 = 0; k0 < 512; k0 += 64) {
    __syncthreads();
#pragma unroll
    for (int i = 0; i < 4; ++i) {
      int idx = tid + 256 * i, row = idx >> 3, seg = idx & 7;
      int sseg = seg ^ (row & 7);  // pre-swizzled source
      gload16(Ag + (size_t)row * 512 + k0 + sseg * 8, Asm + idx * 8);
    }
#pragma unroll
    for (int i = 0; i < 4; ++i) {
      int idx = tid + 256 * i, row = idx >> 3, seg = idx & 7;
      int sseg = seg ^ (row & 7);
      gload16(Bg + (size_t)row * 512 + k0 + sseg * 8, Bsm + idx * 8);
    }
    __syncthreads();
#pragma unroll
    for (int kk = 0; kk < 64; kk += 32) {
      bfrag af[4], bfr[4];
#pragma unroll
      for (int mi = 0; mi < 4; ++mi) {
        int row = wr + mi * 16 + lrow;
        af[mi] = *(const bfrag*)(Asm + row * 64 + ((kk + lk) ^ ((row & 7) << 3)));
      }
#pragma unroll
      for (int ni = 0; ni < 4; ++ni) {
        int row = wc + ni * 16 + lrow;
        bfr[ni] = *(const bfrag*)(Bsm + row * 64 + ((kk + lk) ^ ((row & 7) << 3)));
      }
#pragma unroll
      for (int mi = 0; mi < 4; ++mi)
#pragma unroll
        for (int ni = 0; ni < 4; ++ni)
          acc[mi][ni] = __builtin_amdgcn_mfma_f32_16x16x32_bf16(
              af[mi], bfr[ni], acc[mi][ni], 0, 0, 0);
    }
  }

  // Epilogue: spikes into LDS bounce, exact fallback, then 3MB bitmask.
  __syncthreads();
  short* Cs = Asm;  // reuse: C[128 o][128 t] bf16 spike values
  const int lrg = (lane >> 4) * 4;
  unsigned long long fb = 0;
  bool anyspike = false;
#pragma unroll
  for (int mi = 0; mi < 4; ++mi)
#pragma unroll
    for (int ni = 0; ni < 4; ++ni)
#pragma unroll
      for (int r = 0; r < 4; ++r) {
        int rowl = wr + mi * 16 + lrg + r;
        int coll = wc + ni * 16 + lrow;
        float v = acc[mi][ni][r];
        if (fabsf(v - THRESH) < 0.05f) fb |= 1ull << (mi * 16 + ni * 4 + r);
        else anyspike |= (v >= THRESH);
        Cs[rowl * 128 + coll] = (v >= THRESH) ? (short)0x3F80 : (short)0;
      }
  if (__builtin_expect(fb != 0, 0)) {  // exact fp32 recompute, ~never taken
    for (int bit = 0; bit < 64; ++bit) {
      if (!((fb >> bit) & 1)) continue;
      int mi = bit >> 4, ni = (bit >> 2) & 3, r = bit & 3;
      int rowl = wr + mi * 16 + lrg + r;
      int coll = wc + ni * 16 + lrow;
      const float* wrow = Wf + (size_t)(o0 + rowl) * 512;
      const float* xcol = x + (size_t)b * 512 * 4096 + (size_t)(t0 + coll) * 8;
      float s = 0.f;
      for (int c = 0; c < 512; ++c) {
        const float* xc = xcol + (size_t)c * 4096;
        float p = ((xc[0] + xc[1]) + (xc[2] + xc[3])) +
                  ((xc[4] + xc[5]) + (xc[6] + xc[7]));
        s += wrow[c] * (p * 0.125f);
      }
      bool sp = (s >= THRESH);
      anyspike |= sp;
      Cs[rowl * 128 + coll] = sp ? (short)0x3F80 : (short)0;
    }
  }
  __syncthreads();
  {
    // compress: row = tid>>1 (128 o-rows), half = tid&1 (64 t each)
    const int row = tid >> 1, half = tid & 1;
    unsigned long long bits = 0;
#pragma unroll
    for (int j = 0; j < 8; ++j) {
      bfrag v = *(const bfrag*)(Cs + row * 128 + half * 64 + j * 8);
#pragma unroll
      for (int k = 0; k < 8; ++k)
        bits |= (unsigned long long)(v[k] != 0) << (j * 8 + k);
    }
    *(unsigned long long*)(mask + ((size_t)b * 1536 + o0 + row) * 64 +
                           (t0 >> 3) + half * 8) = bits;
  }
  unsigned long long bal = __ballot(anyspike);
  if (lane == 0 && bal != 0ull) atomicOr(&flags[b], 1);
}

// ------- attention (cold: only for batches with spikes). Expands the spike
// bitmask to bf16/f32; M = V K^T (bf16 MFMA, exact on binary spikes),
// O = scale * M Q (fp32); emits attT f32 + attTb bf16.
__global__ __launch_bounds__(256) void attn_kernel(const uint8_t* __restrict__ mask,
                                                   float* __restrict__ attT,
                                                   short* __restrict__ attTb,
                                                   const int* __restrict__ flags) {
  const int b = blockIdx.z, h = blockIdx.y, th = blockIdx.x;  // th: t-half
  if (flags[b] == 0) return;  // no spikes in this batch -> attn output is 0
  const uint8_t* Qm = mask + ((size_t)b * 1536 + h * 64) * 64;
  const uint8_t* Km = mask + ((size_t)b * 1536 + 512 + h * 64) * 64;
  const uint8_t* Vm = mask + ((size_t)b * 1536 + 1024 + h * 64) * 64;

  __shared__ float Ms[64][65];  // Ms[e][d]
  __shared__ float Qs[64][65];  // Qs[e][tloc]
  __shared__ float Ts[64][65];  // Ts[tloc][d]

  const int tid = threadIdx.x, lane = tid & 63, wave = tid >> 6;
  const int lrow = lane & 15, lk = (lane >> 4) * 8, lrg = (lane >> 4) * 4;

  f32x4 mAcc[4] = {};
  for (int kk = 0; kk < 512; kk += 32) {
    uint8_t mv = Vm[(wave * 16 + lrow) * 64 + ((kk + lk) >> 3)];
    bfrag a;
#pragma unroll
    for (int j = 0; j < 8; ++j) a[j] = ((mv >> j) & 1) ? (short)0x3F80 : (short)0;
#pragma unroll
    for (int ni = 0; ni < 4; ++ni) {
      uint8_t mk = Km[(ni * 16 + lrow) * 64 + ((kk + lk) >> 3)];
      bfrag bb;
#pragma unroll
      for (int j = 0; j < 8; ++j) bb[j] = ((mk >> j) & 1) ? (short)0x3F80 : (short)0;
      mAcc[ni] = __builtin_amdgcn_mfma_f32_16x16x32_bf16(a, bb, mAcc[ni], 0, 0, 0);
    }
  }
#pragma unroll
  for (int ni = 0; ni < 4; ++ni)
#pragma unroll
    for (int r = 0; r < 4; ++r)
      Ms[ni * 16 + lrow][wave * 16 + lrg + r] = mAcc[ni][r];
  __syncthreads();

  const int tx = tid & 15, ty = tid >> 4;
  const int srow = tid >> 2, scseg = (tid & 3) * 16;
  for (int tt = th * 256; tt < th * 256 + 256; tt += 64) {
    {
      uint8_t b0 = Qm[srow * 64 + ((tt + scseg) >> 3)];
      uint8_t b1 = Qm[srow * 64 + ((tt + scseg) >> 3) + 1];
#pragma unroll
      for (int j = 0; j < 8; ++j) {
        Qs[srow][scseg + j] = (float)((b0 >> j) & 1);
        Qs[srow][scseg + 8 + j] = (float)((b1 >> j) & 1);
      }
    }
    __syncthreads();
    float acc[4][4] = {};
#pragma unroll
    for (int e = 0; e < 64; ++e) {
      float4 md = *reinterpret_cast<const float4*>(&Ms[e][ty << 2]);
      float4 qt = *reinterpret_cast<const float4*>(&Qs[e][tx << 2]);
      float mr[4] = {md.x, md.y, md.z, md.w};
      float qr[4] = {qt.x, qt.y, qt.z, qt.w};
#pragma unroll
      for (int i = 0; i < 4; ++i)
#pragma unroll
        for (int j = 0; j < 4; ++j) acc[i][j] += mr[i] * qr[j];
    }
#pragma unroll
    for (int i = 0; i < 4; ++i)
#pragma unroll
      for (int j = 0; j < 4; ++j)
        Ts[(tx << 2) + j][(ty << 2) + i] = acc[i][j] * 0.125f;
    __syncthreads();
    {
      float* dst = attT + ((size_t)b * 512 + tt + srow) * 512 + h * 64 + scseg;
      short* dstb = attTb + ((size_t)b * 512 + tt + srow) * 512 + h * 64 + scseg;
#pragma unroll
      for (int k = 0; k < 4; ++k) {
        float4 v = *reinterpret_cast<const float4*>(&Ts[srow][scseg + 4 * k]);
        *reinterpret_cast<float4*>(dst + 4 * k) = v;
        s16x4 hh;
        hh.x = f2bf(v.x); hh.y = f2bf(v.y); hh.z = f2bf(v.z); hh.w = f2bf(v.w);
        ((s16x4*)dstb)[k] = hh;
      }
    }
    __syncthreads();
  }
}

// ------- out GEMM + BN + spike + repeat8; bias fast path (nontemporal) ------
__global__ __launch_bounds__(256) void out_gemm_mfma(
    const short* __restrict__ Wob, const short* __restrict__ attTb,
    const float* __restrict__ Wf, const float* __restrict__ attT,
    const float* __restrict__ gamma, const float* __restrict__ beta,
    const float* __restrict__ mean, const float* __restrict__ var,
    float* __restrict__ out, const int* __restrict__ flags) {
  const int b = blockIdx.z, o0 = blockIdx.y * 128, t0 = blockIdx.x * 128;
  const int tid = threadIdx.x;

  if (flags[b] == 0) {
    // attn output is exactly 0 -> y = beta - mean*inv, uniform over t (and b).
    __shared__ float sRow[128];
    if (tid < 128) {
      int o = o0 + tid;
      float inv = gamma[o] / sqrtf(var[o] + BN_EPS);
      float y = beta[o] - mean[o] * inv;
      sRow[tid] = (y >= THRESH) ? 1.0f : 0.0f;
    }
    __syncthreads();
    float* base = out + ((size_t)b * 512 + o0) * 4096 + (size_t)t0 * 8;
#pragma unroll 4
    for (int r = 0; r < 128; ++r) {
      float s = sRow[r];
      nt_store4(base + (size_t)r * 4096 + tid * 4, s);
    }
    return;
  }

  __shared__ __align__(16) short Asm[128 * 64];
  __shared__ __align__(16) short Bsm[128 * 64];
  const int lane = tid & 63, wave = tid >> 6;
  const int wr = (wave >> 1) * 64, wc = (wave & 1) * 64;
  const int lrow = lane & 15, lk = (lane >> 4) * 8;
  f32x4 acc[4][4] = {};
  const short* Ag = Wob + (size_t)o0 * 512;
  const short* Bg = attTb + ((size_t)b * 512 + t0) * 512;

  for (int k0 = 0; k0 < 512; k0 += 64) {
    __syncthreads();
#pragma unroll
    for (int i = 0; i < 4; ++i) {
      int idx = tid + 256 * i, row = idx >> 3, seg = idx & 7;
      int sseg = seg ^ (row & 7);
      gload16(Ag + (size_t)row * 512 + k0 + sseg * 8, Asm + idx * 8);
    }
#pragma unroll
    for (int i = 0; i < 4; ++i) {
      int idx = tid + 256 * i, row = idx >> 3, seg = idx & 7;
      int sseg = seg ^ (row & 7);
      gload16(Bg + (size_t)row * 512 + k0 + sseg * 8, Bsm + idx * 8);
    }
    __syncthreads();
#pragma unroll
    for (int kk = 0; kk < 64; kk += 32) {
      bfrag af[4], bfr[4];
#pragma unroll
      for (int mi = 0; mi < 4; ++mi) {
        int row = wr + mi * 16 + lrow;
        af[mi] = *(const bfrag*)(Asm + row * 64 + ((kk + lk) ^ ((row & 7) << 3)));
      }
#pragma unroll
      for (int ni = 0; ni < 4; ++ni) {
        int row = wc + ni * 16 + lrow;
        bfr[ni] = *(const bfrag*)(Bsm + row * 64 + ((kk + lk) ^ ((row & 7) << 3)));
      }
#pragma unroll
      for (int mi = 0; mi < 4; ++mi)
#pragma unroll
        for (int ni = 0; ni < 4; ++ni)
          acc[mi][ni] = __builtin_amdgcn_mfma_f32_16x16x32_bf16(
              af[mi], bfr[ni], acc[mi][ni], 0, 0, 0);
    }
  }

  const int lrg = (lane >> 4) * 4;
  unsigned long long fbm = 0;
#pragma unroll
  for (int mi = 0; mi < 4; ++mi)
#pragma unroll
    for (int r = 0; r < 4; ++r) {
      const int o = o0 + wr + mi * 16 + lrg + r;
      const float inv = gamma[o] / sqrtf(var[o] + BN_EPS);
      const float bias = beta[o] - mean[o] * inv;
#pragma unroll
      for (int ni = 0; ni < 4; ++ni) {
        int tt = t0 + wc + ni * 16 + lrow;
        float y = acc[mi][ni][r] * inv + bias;
        if (fabsf(y - THRESH) < 0.02f) fbm |= 1ull << (mi * 16 + ni * 4 + r);
        float s = (y >= THRESH) ? 1.0f : 0.0f;
        float* dp = out + ((size_t)b * 512 + o) * 4096 + (size_t)tt * 8;
        nt_store4(dp, s);
        nt_store4(dp + 4, s);
      }
    }
  if (__builtin_expect(fbm != 0, 0)) {  // exact fp32 recompute, ~never taken
    for (int bit = 0; bit < 64; ++bit) {
      if (!((fbm >> bit) & 1)) continue;
      int mi = bit >> 4, ni = (bit >> 2) & 3, r = bit & 3;
      int o = o0 + wr + mi * 16 + lrg + r;
      int tt = t0 + wc + ni * 16 + lrow;
      const float* wrow = Wf + (size_t)o * 512;
      const float* arow = attT + ((size_t)b * 512 + tt) * 512;
      float s = 0.f;
      for (int c = 0; c < 512; ++c) s += wrow[c] * arow[c];
      float inv = gamma[o] / sqrtf(var[o] + BN_EPS);
      float y = s * inv + (beta[o] - mean[o] * inv);
      float sp = (y >= THRESH) ? 1.0f : 0.0f;
      float* dp = out + ((size_t)b * 512 + o) * 4096 + (size_t)tt * 8;
      nt_store4(dp, sp);
      nt_store4(dp + 4, sp);
    }
  }
}

extern "C" void kernel_launch(void* const* d_in, const int* in_sizes, int n_in,
                              void* d_out, int out_size, void* d_ws, size_t ws_size,
                              hipStream_t stream) {
  (void)in_sizes; (void)n_in; (void)out_size; (void)ws_size;
  const float* x     = (const float*)d_in[0];
  const float* w_qkv = (const float*)d_in[1];
  const float* w_out = (const float*)d_in[2];
  const float* gamma = (const float*)d_in[3];
  const float* beta  = (const float*)d_in[4];
  const float* mean  = (const float*)d_in[5];
  const float* var   = (const float*)d_in[6];
  float* outp = (float*)d_out;

  // d_out-front scratch: xpT bf16 (32,512t,512c) in [0,16MB) — consumed by
  // qkv BEFORE out_gemm writes d_out.
  // d_ws scratch (out_gemm inputs must NOT alias d_out):
  //   [0,32MB)   attT  f32  (32,512t,512c)
  //   [32,48MB)  attTb bf16 (32,512t,512c)
  //   [48MB)     Wqb bf16 (1536,512), [50MB) Wob bf16 (512,512),
  //   [51MB)     flags int[32], [52MB,+3MB) spike bitmask (32,1536,64B)
  char* ob = (char*)d_out;
  char* wb = (char*)d_ws;
  short* xpT  = (short*)(ob);
  float* attT  = (float*)(wb);
  short* attTb = (short*)(wb + ((size_t)32 << 20));
  short* Wqb   = (short*)(wb + ((size_t)48 << 20));
  short* Wob   = (short*)(wb + ((size_t)50 << 20));
  int*   flags = (int*)(wb + ((size_t)51 << 20));
  uint8_t* mask = (uint8_t*)(wb + ((size_t)52 << 20));

  pool_wconv_kernel<<<dim3(8, 8, 33), 256, 0, stream>>>(x, xpT, w_qkv, w_out,
                                                        Wqb, Wob, flags);
  qkv_gemm_mfma<<<dim3(4, 12, 32), 256, 0, stream>>>(Wqb, xpT, w_qkv, x, mask,
                                                     flags);
  attn_kernel<<<dim3(2, 8, 32), 256, 0, stream>>>(mask, attT, attTb, flags);
  out_gemm_mfma<<<dim3(4, 4, 32), 256, 0, stream>>>(Wob, attTb, w_out, attT,
                                                    gamma, beta, mean, var,
                                                    outp, flags);
}